// Round 2
// baseline (2243.853 us; speedup 1.0000x reference)
//
#include <hip/hip_runtime.h>

#define NN 100000
#define NE 1600000
#define FIN 128
#define FH 48
#define FO 32

// ---------------- degree / normalization ----------------

__global__ __launch_bounds__(256) void k_init_deg(float* __restrict__ deg) {
  int i = blockIdx.x * 256 + threadIdx.x;
  if (i < NN) deg[i] = 1.0f;  // self-loop
}

__global__ __launch_bounds__(256) void k_deg(const int* __restrict__ dst, float* __restrict__ deg) {
  int i = blockIdx.x * 256 + threadIdx.x;
  if (i < NE) atomicAdd(&deg[dst[i]], 1.0f);
}

__global__ __launch_bounds__(256) void k_dinv(const float* __restrict__ deg, float* __restrict__ dinv) {
  int i = blockIdx.x * 256 + threadIdx.x;
  if (i < NN) dinv[i] = rsqrtf(deg[i]);  // deg >= 1 always (self-loop)
}

// norm[e] = dinv[src]*dinv[dst], computed once, reused by both scatters
__global__ __launch_bounds__(256) void k_norm(const int* __restrict__ src, const int* __restrict__ dst,
                                              const float* __restrict__ dinv, float* __restrict__ norm) {
  int i = blockIdx.x * 256 + threadIdx.x;
  if (i < NE) norm[i] = dinv[src[i]] * dinv[dst[i]];
}

// ---------------- layer-1 dense: t1 = x @ W1 ; agg1 = t1 * dinv^2 ----------------
// 64 rows/block, x tile staged in LDS (padded stride 132), W1 (128x48) in LDS,
// each thread computes 12 contiguous cols via float4 LDS reads.

__global__ __launch_bounds__(256) void k_gemm1(const float* __restrict__ x, const float* __restrict__ W1,
                                               const float* __restrict__ dinv,
                                               float* __restrict__ t1, float* __restrict__ agg1) {
  __shared__ float xs[64][132];
  __shared__ float ws[FIN][FH];
  const int t = threadIdx.x;
  const int row0 = blockIdx.x * 64;

  for (int i = t; i < FIN * FH; i += 256) ws[i / FH][i % FH] = W1[i];
  for (int i = t; i < 64 * (FIN / 4); i += 256) {
    int r = i >> 5, c4 = i & 31;
    float4 v = make_float4(0.f, 0.f, 0.f, 0.f);
    if (row0 + r < NN) v = ((const float4*)x)[(size_t)(row0 + r) * (FIN / 4) + c4];
    xs[r][c4 * 4 + 0] = v.x; xs[r][c4 * 4 + 1] = v.y;
    xs[r][c4 * 4 + 2] = v.z; xs[r][c4 * 4 + 3] = v.w;
  }
  __syncthreads();

  const int row = t >> 2;          // 0..63
  const int cg  = (t & 3) * 12;    // 12 contiguous output cols
  float acc[12];
  #pragma unroll
  for (int j = 0; j < 12; ++j) acc[j] = 0.f;

  #pragma unroll 4
  for (int k = 0; k < FIN; ++k) {
    float xv = xs[row][k];
    const float4* wp = (const float4*)&ws[k][cg];  // 16B-aligned: k*192 + {0,48,96,144}
    float4 w0 = wp[0], w1 = wp[1], w2 = wp[2];
    acc[0] += xv * w0.x; acc[1] += xv * w0.y; acc[2]  += xv * w0.z; acc[3]  += xv * w0.w;
    acc[4] += xv * w1.x; acc[5] += xv * w1.y; acc[6]  += xv * w1.z; acc[7]  += xv * w1.w;
    acc[8] += xv * w2.x; acc[9] += xv * w2.y; acc[10] += xv * w2.z; acc[11] += xv * w2.w;
  }

  const int grow = row0 + row;
  if (grow < NN) {
    float di = dinv[grow];
    float sn = di * di;  // self-loop norm
    float* tp = t1   + (size_t)grow * FH + cg;
    float* ap = agg1 + (size_t)grow * FH + cg;
    #pragma unroll
    for (int j = 0; j < 12; ++j) { tp[j] = acc[j]; ap[j] = acc[j] * sn; }
  }
}

// ---------------- edge scatter: agg[dst] += norm[e] * feat[src] ----------------
// 12 threads per edge, float4 gather + 4 scalar f32 atomics each.

template <bool PRENORM>
__global__ __launch_bounds__(256) void k_scatter(const int* __restrict__ src, const int* __restrict__ dst,
                                                 const float* __restrict__ dinv, const float* __restrict__ norm,
                                                 const float* __restrict__ feat, float* __restrict__ agg) {
  int i = blockIdx.x * 256 + threadIdx.x;
  if (i >= NE * 12) return;
  int e  = i / 12;
  int f4 = i - e * 12;
  int s = src[e], d = dst[e];
  float nv;
  if (PRENORM) nv = norm[e];
  else         nv = dinv[s] * dinv[d];
  float4 v = ((const float4*)feat)[(size_t)s * 12 + f4];
  float* ap = agg + (size_t)d * FH + f4 * 4;
  atomicAdd(ap + 0, nv * v.x);
  atomicAdd(ap + 1, nv * v.y);
  atomicAdd(ap + 2, nv * v.z);
  atomicAdd(ap + 3, nv * v.w);
}

// ---------------- h = relu(agg1 + b1) ; agg2 = h * dinv^2 (float4 over FH=48) ----------------

__global__ __launch_bounds__(256) void k_relu_init(const float* __restrict__ agg1, const float* __restrict__ b1,
                                                   const float* __restrict__ dinv,
                                                   float* __restrict__ h, float* __restrict__ agg2) {
  int i = blockIdx.x * 256 + threadIdx.x;     // one float4 per thread
  if (i >= NN * (FH / 4)) return;
  int row = i / (FH / 4);
  int c4 = i - row * (FH / 4);
  float4 v = ((const float4*)agg1)[i];
  const float4 bb = ((const float4*)b1)[c4];
  v.x = fmaxf(v.x + bb.x, 0.f);
  v.y = fmaxf(v.y + bb.y, 0.f);
  v.z = fmaxf(v.z + bb.z, 0.f);
  v.w = fmaxf(v.w + bb.w, 0.f);
  ((float4*)h)[i] = v;
  float di = dinv[row];
  float sn = di * di;
  float4 a = make_float4(v.x * sn, v.y * sn, v.z * sn, v.w * sn);
  ((float4*)agg2)[i] = a;
}

// ---------------- final dense: mu = agg2@Wmu + bmu ; logstd = agg2@Wls + bls ----------------

__global__ __launch_bounds__(256) void k_gemm2(const float* __restrict__ agg2,
                                               const float* __restrict__ Wmu, const float* __restrict__ bmu,
                                               const float* __restrict__ Wls, const float* __restrict__ bls,
                                               float* __restrict__ out) {
  __shared__ float wmu[FH][FO];
  __shared__ float wls[FH][FO];
  __shared__ float as[8][FH + 1];
  const int t = threadIdx.x;
  for (int i = t; i < FH * FO; i += 256) { wmu[i / FO][i % FO] = Wmu[i]; wls[i / FO][i % FO] = Wls[i]; }
  const int row0 = blockIdx.x * 8;
  for (int i = t; i < 8 * FH; i += 256) {
    int r = i / FH, c = i - r * FH;
    as[r][c] = (row0 + r < NN) ? agg2[(size_t)(row0 + r) * FH + c] : 0.f;
  }
  __syncthreads();
  const int r = t >> 5;   // 8 rows
  const int c = t & 31;   // 32 cols
  float amu = bmu[c], als = bls[c];
  #pragma unroll
  for (int k = 0; k < FH; ++k) {
    float a = as[r][k];
    amu += a * wmu[k][c];
    als += a * wls[k][c];
  }
  const int grow = row0 + r;
  if (grow < NN) {
    out[(size_t)grow * FO + c] = amu;                       // mu
    out[(size_t)NN * FO + (size_t)grow * FO + c] = als;     // logstd
  }
}

// ---------------- launch ----------------

extern "C" void kernel_launch(void* const* d_in, const int* in_sizes, int n_in,
                              void* d_out, int out_size, void* d_ws, size_t ws_size,
                              hipStream_t stream) {
  const float* x   = (const float*)d_in[0];
  const int*   ei  = (const int*)d_in[1];   // [2, NE] flat: src then dst
  const float* W1  = (const float*)d_in[2];
  const float* b1  = (const float*)d_in[3];
  const float* Wmu = (const float*)d_in[4];
  const float* bmu = (const float*)d_in[5];
  const float* Wls = (const float*)d_in[6];
  const float* bls = (const float*)d_in[7];
  float* out = (float*)d_out;

  const int* src = ei;
  const int* dst = ei + NE;

  float* ws   = (float*)d_ws;
  float* deg  = ws;                          // NN
  float* dinv = ws + NN;                     // NN
  float* t1   = ws + 2 * (size_t)NN;         // NN*FH
  float* agg1 = t1 + (size_t)NN * FH;        // NN*FH
  float* h    = agg1 + (size_t)NN * FH;      // NN*FH
  float* agg2 = h + (size_t)NN * FH;         // NN*FH
  float* norm = agg2 + (size_t)NN * FH;      // NE (optional, +6.4MB; total ~84MB)

  const bool use_norm =
      ws_size >= (2 * (size_t)NN + 4 * (size_t)NN * FH + (size_t)NE) * sizeof(float);

  k_init_deg<<<(NN + 255) / 256, 256, 0, stream>>>(deg);
  k_deg<<<(NE + 255) / 256, 256, 0, stream>>>(dst, deg);
  k_dinv<<<(NN + 255) / 256, 256, 0, stream>>>(deg, dinv);
  if (use_norm)
    k_norm<<<(NE + 255) / 256, 256, 0, stream>>>(src, dst, dinv, norm);
  k_gemm1<<<(NN + 63) / 64, 256, 0, stream>>>(x, W1, dinv, t1, agg1);
  if (use_norm) {
    k_scatter<true><<<(NE * 12 + 255) / 256, 256, 0, stream>>>(src, dst, dinv, norm, t1, agg1);
  } else {
    k_scatter<false><<<(NE * 12 + 255) / 256, 256, 0, stream>>>(src, dst, dinv, norm, t1, agg1);
  }
  k_relu_init<<<(NN * (FH / 4) + 255) / 256, 256, 0, stream>>>(agg1, b1, dinv, h, agg2);
  if (use_norm) {
    k_scatter<true><<<(NE * 12 + 255) / 256, 256, 0, stream>>>(src, dst, dinv, norm, h, agg2);
  } else {
    k_scatter<false><<<(NE * 12 + 255) / 256, 256, 0, stream>>>(src, dst, dinv, norm, h, agg2);
  }
  k_gemm2<<<(NN + 7) / 8, 256, 0, stream>>>(agg2, Wmu, bmu, Wls, bls, out);
}

// Round 3
// 449.208 us; speedup vs baseline: 4.9951x; 4.9951x over previous
//
#include <hip/hip_runtime.h>

#define NN 100000
#define NE 1600000
#define FIN 128
#define FH 48
#define FO 32
#define NB 391                      // ceil(NN/256) scan blocks
#define NODES_PER_BLOCK 21          // 12 threads/node, 252 of 256 threads active

// ---------------- degree / normalization / CSR build ----------------

__global__ __launch_bounds__(256) void k_zero(int* __restrict__ deg_i) {
  int i = blockIdx.x * 256 + threadIdx.x;
  if (i < NN) deg_i[i] = 0;
}

__global__ __launch_bounds__(256) void k_hist(const int* __restrict__ dst, int* __restrict__ deg_i) {
  int i = blockIdx.x * 256 + threadIdx.x;
  if (i < NE) atomicAdd(&deg_i[dst[i]], 1);
}

__global__ __launch_bounds__(256) void k_dinv(const int* __restrict__ deg_i, float* __restrict__ dinv) {
  int i = blockIdx.x * 256 + threadIdx.x;
  if (i < NN) dinv[i] = rsqrtf((float)deg_i[i] + 1.0f);  // +1 self-loop
}

// scan pass 1: per-block sums of deg_i
__global__ __launch_bounds__(256) void k_scan1(const int* __restrict__ deg_i, int* __restrict__ bsum) {
  __shared__ int s[256];
  int t = threadIdx.x, i = blockIdx.x * 256 + t;
  s[t] = (i < NN) ? deg_i[i] : 0;
  __syncthreads();
  for (int o = 128; o > 0; o >>= 1) { if (t < o) s[t] += s[t + o]; __syncthreads(); }
  if (t == 0) bsum[blockIdx.x] = s[0];
}

// scan pass 2: serial exclusive scan of NB block sums (NB=391, ~µs)
__global__ void k_scan2(int* __restrict__ bsum, int* __restrict__ off) {
  if (threadIdx.x == 0 && blockIdx.x == 0) {
    int run = 0;
    for (int b = 0; b < NB; ++b) { int v = bsum[b]; bsum[b] = run; run += v; }
    off[NN] = run;  // == NE
  }
}

// scan pass 3: in-block Hillis-Steele -> exclusive offsets; cursor copy for binning
__global__ __launch_bounds__(256) void k_scan3(const int* __restrict__ deg_i, const int* __restrict__ bsum,
                                               int* __restrict__ off, int* __restrict__ cursor) {
  __shared__ int s[256];
  int t = threadIdx.x, i = blockIdx.x * 256 + t;
  int v = (i < NN) ? deg_i[i] : 0;
  s[t] = v;
  __syncthreads();
  for (int o = 1; o < 256; o <<= 1) {
    int a = (t >= o) ? s[t - o] : 0;
    __syncthreads();
    s[t] += a;
    __syncthreads();
  }
  int excl = s[t] - v + bsum[blockIdx.x];
  if (i < NN) { off[i] = excl; cursor[i] = excl; }
}

// bin edges by dst: csr[pos] = {src, bits(dinv[src]*dinv[dst])}
__global__ __launch_bounds__(256) void k_bin(const int* __restrict__ src, const int* __restrict__ dst,
                                             const float* __restrict__ dinv,
                                             int* __restrict__ cursor, int2* __restrict__ csr) {
  int e = blockIdx.x * 256 + threadIdx.x;
  if (e >= NE) return;
  int s = src[e], d = dst[e];
  float nv = dinv[s] * dinv[d];
  int pos = atomicAdd(&cursor[d], 1);
  csr[pos] = make_int2(s, __float_as_int(nv));
}

// ---------------- layer-1 dense: t1 = x @ W1 ----------------
// 64 rows/block, x tile in LDS (pad 132), W1 (128x48) in LDS, 12 cols/thread.

__global__ __launch_bounds__(256) void k_gemm1(const float* __restrict__ x, const float* __restrict__ W1,
                                               float* __restrict__ t1) {
  __shared__ float xs[64][132];
  __shared__ float ws[FIN][FH];
  const int t = threadIdx.x;
  const int row0 = blockIdx.x * 64;

  for (int i = t; i < FIN * FH; i += 256) ws[i / FH][i % FH] = W1[i];
  for (int i = t; i < 64 * (FIN / 4); i += 256) {
    int r = i >> 5, c4 = i & 31;
    float4 v = make_float4(0.f, 0.f, 0.f, 0.f);
    if (row0 + r < NN) v = ((const float4*)x)[(size_t)(row0 + r) * (FIN / 4) + c4];
    xs[r][c4 * 4 + 0] = v.x; xs[r][c4 * 4 + 1] = v.y;
    xs[r][c4 * 4 + 2] = v.z; xs[r][c4 * 4 + 3] = v.w;
  }
  __syncthreads();

  const int row = t >> 2;
  const int cg  = (t & 3) * 12;
  float acc[12];
  #pragma unroll
  for (int j = 0; j < 12; ++j) acc[j] = 0.f;

  #pragma unroll 4
  for (int k = 0; k < FIN; ++k) {
    float xv = xs[row][k];
    const float4* wp = (const float4*)&ws[k][cg];
    float4 w0 = wp[0], w1 = wp[1], w2 = wp[2];
    acc[0] += xv * w0.x; acc[1] += xv * w0.y; acc[2]  += xv * w0.z; acc[3]  += xv * w0.w;
    acc[4] += xv * w1.x; acc[5] += xv * w1.y; acc[6]  += xv * w1.z; acc[7]  += xv * w1.w;
    acc[8] += xv * w2.x; acc[9] += xv * w2.y; acc[10] += xv * w2.z; acc[11] += xv * w2.w;
  }

  const int grow = row0 + row;
  if (grow < NN) {
    float* tp = t1 + (size_t)grow * FH + cg;
    #pragma unroll
    for (int j = 0; j < 12; ++j) tp[j] = acc[j];
  }
}

// ---------------- CSR gather aggregation: out-row = dinv^2*feat[n] + sum norm*feat[src] ----------------
// 12 threads per node (one float4 lane each); atomic-free, one streaming write per row.
// RELU=true: out = relu(acc + bias)  (layer-1 epilogue)

template <bool RELU>
__global__ __launch_bounds__(256) void k_gather(const int* __restrict__ off, const int2* __restrict__ csr,
                                                const float* __restrict__ feat, const float* __restrict__ dinv,
                                                const float* __restrict__ bias, float* __restrict__ out) {
  const int t = threadIdx.x;
  if (t >= NODES_PER_BLOCK * 12) return;
  const int local = t / 12;
  const int f4 = t - local * 12;
  const int node = blockIdx.x * NODES_PER_BLOCK + local;
  if (node >= NN) return;

  const float4* feat4 = (const float4*)feat;
  float di = dinv[node];
  float sn = di * di;
  float4 v = feat4[(size_t)node * 12 + f4];
  float4 acc = make_float4(v.x * sn, v.y * sn, v.z * sn, v.w * sn);

  int j = off[node];
  const int jend = off[node + 1];
  for (; j + 4 <= jend; j += 4) {
    int2 c0 = csr[j], c1 = csr[j + 1], c2 = csr[j + 2], c3 = csr[j + 3];
    float4 v0 = feat4[(size_t)c0.x * 12 + f4];
    float4 v1 = feat4[(size_t)c1.x * 12 + f4];
    float4 v2 = feat4[(size_t)c2.x * 12 + f4];
    float4 v3 = feat4[(size_t)c3.x * 12 + f4];
    float n0 = __int_as_float(c0.y), n1 = __int_as_float(c1.y);
    float n2 = __int_as_float(c2.y), n3 = __int_as_float(c3.y);
    acc.x += n0 * v0.x; acc.y += n0 * v0.y; acc.z += n0 * v0.z; acc.w += n0 * v0.w;
    acc.x += n1 * v1.x; acc.y += n1 * v1.y; acc.z += n1 * v1.z; acc.w += n1 * v1.w;
    acc.x += n2 * v2.x; acc.y += n2 * v2.y; acc.z += n2 * v2.z; acc.w += n2 * v2.w;
    acc.x += n3 * v3.x; acc.y += n3 * v3.y; acc.z += n3 * v3.z; acc.w += n3 * v3.w;
  }
  for (; j < jend; ++j) {
    int2 c = csr[j];
    float4 vv = feat4[(size_t)c.x * 12 + f4];
    float nv = __int_as_float(c.y);
    acc.x += nv * vv.x; acc.y += nv * vv.y; acc.z += nv * vv.z; acc.w += nv * vv.w;
  }

  if (RELU) {
    const float4 bb = ((const float4*)bias)[f4];
    acc.x = fmaxf(acc.x + bb.x, 0.f);
    acc.y = fmaxf(acc.y + bb.y, 0.f);
    acc.z = fmaxf(acc.z + bb.z, 0.f);
    acc.w = fmaxf(acc.w + bb.w, 0.f);
  }
  ((float4*)out)[(size_t)node * 12 + f4] = acc;
}

// ---------------- final dense: mu = agg2@Wmu + bmu ; logstd = agg2@Wls + bls ----------------

__global__ __launch_bounds__(256) void k_gemm2(const float* __restrict__ agg2,
                                               const float* __restrict__ Wmu, const float* __restrict__ bmu,
                                               const float* __restrict__ Wls, const float* __restrict__ bls,
                                               float* __restrict__ out) {
  __shared__ float wmu[FH][FO];
  __shared__ float wls[FH][FO];
  __shared__ float as[8][FH + 1];
  const int t = threadIdx.x;
  for (int i = t; i < FH * FO; i += 256) { wmu[i / FO][i % FO] = Wmu[i]; wls[i / FO][i % FO] = Wls[i]; }
  const int row0 = blockIdx.x * 8;
  for (int i = t; i < 8 * FH; i += 256) {
    int r = i / FH, c = i - r * FH;
    as[r][c] = (row0 + r < NN) ? agg2[(size_t)(row0 + r) * FH + c] : 0.f;
  }
  __syncthreads();
  const int r = t >> 5;
  const int c = t & 31;
  float amu = bmu[c], als = bls[c];
  #pragma unroll
  for (int k = 0; k < FH; ++k) {
    float a = as[r][k];
    amu += a * wmu[k][c];
    als += a * wls[k][c];
  }
  const int grow = row0 + r;
  if (grow < NN) {
    out[(size_t)grow * FO + c] = amu;                       // mu
    out[(size_t)NN * FO + (size_t)grow * FO + c] = als;     // logstd
  }
}

// ---------------- launch ----------------

extern "C" void kernel_launch(void* const* d_in, const int* in_sizes, int n_in,
                              void* d_out, int out_size, void* d_ws, size_t ws_size,
                              hipStream_t stream) {
  const float* x   = (const float*)d_in[0];
  const int*   ei  = (const int*)d_in[1];   // [2, NE] flat: src then dst
  const float* W1  = (const float*)d_in[2];
  const float* b1  = (const float*)d_in[3];
  const float* Wmu = (const float*)d_in[4];
  const float* bmu = (const float*)d_in[5];
  const float* Wls = (const float*)d_in[6];
  const float* bls = (const float*)d_in[7];
  float* out = (float*)d_out;

  const int* src = ei;
  const int* dst = ei + NE;

  // workspace layout (~72 MB, all 16B-aligned)
  char* base = (char*)d_ws;
  int2*  csr    = (int2*)base;                         // NE*8   = 12,800,000 B
  float* t1     = (float*)(base + (size_t)NE * 8);     // NN*FH*4 = 19.2 MB
  float* h      = t1 + (size_t)NN * FH;                // 19.2 MB
  float* agg2   = h + (size_t)NN * FH;                 // 19.2 MB
  int*   deg_i  = (int*)(agg2 + (size_t)NN * FH);      // NN
  float* dinv   = (float*)(deg_i + NN);                // NN
  int*   off    = (int*)(dinv + NN);                   // NN+1
  int*   cursor = off + NN + 1;                        // NN
  int*   bsum   = cursor + NN;                         // NB

  // CSR build
  k_zero <<<(NN + 255) / 256, 256, 0, stream>>>(deg_i);
  k_hist <<<(NE + 255) / 256, 256, 0, stream>>>(dst, deg_i);
  k_dinv <<<(NN + 255) / 256, 256, 0, stream>>>(deg_i, dinv);
  k_scan1<<<NB, 256, 0, stream>>>(deg_i, bsum);
  k_scan2<<<1, 64, 0, stream>>>(bsum, off);
  k_scan3<<<NB, 256, 0, stream>>>(deg_i, bsum, off, cursor);
  k_bin  <<<(NE + 255) / 256, 256, 0, stream>>>(src, dst, dinv, cursor, csr);

  // layer 1: t1 = x@W1 ; h = relu(Ahat*t1 + b1)
  k_gemm1<<<(NN + 63) / 64, 256, 0, stream>>>(x, W1, t1);
  k_gather<true><<<(NN + NODES_PER_BLOCK - 1) / NODES_PER_BLOCK, 256, 0, stream>>>(off, csr, t1, dinv, b1, h);

  // layer 2: agg2 = Ahat*h ; out = agg2@{Wmu,Wls} + {bmu,bls}
  k_gather<false><<<(NN + NODES_PER_BLOCK - 1) / NODES_PER_BLOCK, 256, 0, stream>>>(off, csr, h, dinv, b1, agg2);
  k_gemm2<<<(NN + 7) / 8, 256, 0, stream>>>(agg2, Wmu, bmu, Wls, bls, out);
}